// Round 18
// baseline (202.823 us; speedup 1.0000x reference)
//
#include <hip/hip_runtime.h>
#include <hip/hip_bf16.h>
#include <math.h>

#define NIMG 1024
#define NPATCH 64
#define PDIM 192
#define KCODES 4096
#define EDIM 2048
#define VDIM 2048
#define MROWS (NIMG * NPATCH)   // 65536
#define KP 192                  // fp16 single-term: K = 192
#define NKS 6                   // K-steps (BK=32) per column tile
#define NCT 32                  // column tiles of 128 codes

typedef _Float16 f16x8 __attribute__((ext_vector_type(8)));
typedef __attribute__((ext_vector_type(4))) float f32x4;

__device__ __forceinline__ void gload_lds16(const void* g, void* l) {
    __builtin_amdgcn_global_load_lds(
        (const __attribute__((address_space(1))) unsigned int*)g,
        (__attribute__((address_space(3))) unsigned int*)l,
        16, 0, 0);
}

__device__ __forceinline__ void merge_top2(float& v1, int& i1, float& v2, int& i2,
                                           float ov1, int oi1, float ov2, int oi2) {
    bool aw = (v1 > ov1) || (v1 == ov1 && i1 < oi1);
    float w1v = aw ? v1 : ov1;  int w1i = aw ? i1 : oi1;
    float c2v = aw ? v2 : ov2;  int c2i = aw ? i2 : oi2;   // winner's own #2
    float l1v = aw ? ov1 : v1;  int l1i = aw ? oi1 : i1;   // loser's #1
    bool bw = (c2v > l1v) || (c2v == l1v && c2i < l1i);
    v1 = w1v; i1 = w1i;
    v2 = bw ? c2v : l1v; i2 = bw ? c2i : l1i;
}

// packed-key top-2 fold: 3 VALU (min_i32 + 2 max_i32)
__device__ __forceinline__ void kfold(int& t1, int& t2, int key) {
    int m = (key < t1) ? key : t1;
    t2 = (t2 > m) ? t2 : m;
    t1 = (t1 > key) ? t1 : key;
}

// ---------------- prep: codebook -> fp16, [4096][192], vectorized ----------------
__global__ __launch_bounds__(256) void prep_codebook_kernel(
    const float* __restrict__ cb, unsigned short* __restrict__ Bh)
{
    int i = (blockIdx.x * 256 + threadIdx.x) * 8;
    if (i >= KCODES * PDIM) return;
    float4 u = *(const float4*)(cb + i);
    float4 v = *(const float4*)(cb + i + 4);
    f16x8 h;
    h[0] = (_Float16)u.x; h[1] = (_Float16)u.y; h[2] = (_Float16)u.z; h[3] = (_Float16)u.w;
    h[4] = (_Float16)v.x; h[5] = (_Float16)v.y; h[6] = (_Float16)v.z; h[7] = (_Float16)v.w;
    *(f16x8*)(Bh + i) = h;
}

// ---------------- fp16 MFMA GEMM (16x16x32, K=192) + fused prep + top-2 ----
// r18: 128x128 block tile, 4 waves (2M x 2N), wave tile 64x64 (acc = 64 AGPR).
// LDS = A panel 48 KB resident + B 3-ring 24 KB = 72 KB -> TWO blocks/CU with
// INDEPENDENT barrier domains (regs ~174 <= 256, so both fit — the r13/r14
// idea made register-feasible). One block's MFMA covers the other's drains.
// Within a block: r16's proven schedule — 2-phase lgkm-fenced MFMA clusters,
// distance-2 vmcnt(2) B-ring, A-frag prefetch in the step tail, in-block
// pixel prep (2 images) with step-0/1 B staged before prep.
__global__ __launch_bounds__(256, 2) void gemm_top2_kernel(
    const float* __restrict__ pixels, const unsigned short* __restrict__ B,
    float* __restrict__ o1v, int* __restrict__ o1i,
    float* __restrict__ o2v, int* __restrict__ o2i)
{
    __shared__ unsigned short Asl[6][4096];   // 48 KB: A, tile j = K [32j,32j+32)
    __shared__ unsigned short Bsl[3][4096];   // 24 KB: B ring (128 cols x 32 k)

    const int t = threadIdx.x;          // 0..255
    const int w = t >> 6;               // wave 0..3
    const int l = t & 63;
    const int lo4 = l & 15, hi4 = l >> 4;
    const int wr = w >> 1, wc = w & 1;  // 2M x 2N wave grid
    const int m0 = blockIdx.x * 128;

    // staging coords for B: thread t covers 16B chunk t (cols 0..63) and +256
    const int srow = t >> 2;                      // 0..63
    const int kc   = (t & 3) ^ ((srow >> 1) & 3); // swizzled k-chunk (involution)
    const unsigned short* b0b = B + (size_t)srow * KP + kc * 8;

    auto stageB = [&](int sct, int sj, int sbuf) {   // 8 KB tile: 2 issues
        char* Bd = (char*)Bsl[sbuf] + w * 1024;
        const unsigned short* gb = b0b + sct * (128 * KP) + sj * 32;
        gload_lds16(gb, Bd);
        gload_lds16(gb + 64 * KP, Bd + 4096);
    };

    // ---- issue step-0/1 B loads FIRST (latency hides under prep) ----
    stageB(0, 0, 0);
    stageB(0, 1, 1);

    // ---- fused A prep: 2 images -> normalized fp16 panel in LDS ----
    const float* pixb = pixels + (size_t)(m0 >> 6) * 12288;   // 2 images
    const int prow = t & 127;                   // my A row (0..127)
    {
        // 1) norm partial sums: thread t covers half (t>>7) of row prow
        int p = prow & 63;
        const float* pp = pixb + (size_t)(prow >> 6) * 12288 + (p >> 3) * 512 + (p & 7) * 8;
        const int m0c = (t >> 7) * 12;
        float s = 0.f;
        #pragma unroll
        for (int q = 0; q < 12; ++q) {
            int m = m0c + q;                     // segment 0..23 (8 floats)
            const float* src = pp + (m >> 3) * 4096 + (m & 7) * 64;
            float4 u = *(const float4*)src, v = *(const float4*)(src + 4);
            s += u.x*u.x + u.y*u.y + u.z*u.z + u.w*u.w
               + v.x*v.x + v.y*v.y + v.z*v.z + v.w*v.w;
        }
        ((float*)Asl)[t] = s;                    // [256] partials
        asm volatile("s_waitcnt lgkmcnt(0)" ::: "memory");
        __builtin_amdgcn_s_barrier();            // raw: don't drain B gloads
        float tot = ((float*)Asl)[prow] + ((float*)Asl)[128 + prow];
        float rinv = 1.f / fmaxf(sqrtf(tot), 1e-8f);
        asm volatile("s_waitcnt lgkmcnt(0)" ::: "memory");
        __builtin_amdgcn_s_barrier();            // partial reads done before overwrite
        // 2) write A panel (halves of row prow: chunks 0-11 / 12-23)
        #pragma unroll
        for (int q = 0; q < 12; ++q) {
            int ch = m0c + q;                    // k-chunk 0..23 (8 elems)
            const float* src = pp + (ch >> 3) * 4096 + (ch & 7) * 64;
            float4 u = *(const float4*)src, v = *(const float4*)(src + 4);
            f16x8 hv;
            hv[0] = (_Float16)(u.x * rinv); hv[1] = (_Float16)(u.y * rinv);
            hv[2] = (_Float16)(u.z * rinv); hv[3] = (_Float16)(u.w * rinv);
            hv[4] = (_Float16)(v.x * rinv); hv[5] = (_Float16)(v.y * rinv);
            hv[6] = (_Float16)(v.z * rinv); hv[7] = (_Float16)(v.w * rinv);
            int j = ch >> 2, c = ch & 3;
            *(f16x8*)&Asl[j][prow * 32 + ((c ^ ((prow >> 1) & 3)) * 8)] = hv;
        }
    }

    // LDS read offsets (ushort units within one 4096-ushort k-32 tile)
    int aoff[4], boff[4];
    #pragma unroll
    for (int rt = 0; rt < 4; ++rt) {
        int row = wr * 64 + rt * 16 + lo4;
        aoff[rt] = row * 32 + (hi4 ^ ((row >> 1) & 3)) * 8;
    }
    #pragma unroll
    for (int cf = 0; cf < 4; ++cf) {
        int col = wc * 64 + cf * 16 + lo4;
        boff[cf] = col * 32 + (hi4 ^ ((col >> 1) & 3)) * 8;
    }

    int t1k[16], t2k[16];
    #pragma unroll
    for (int e = 0; e < 16; ++e) { t1k[e] = (int)0x80000000; t2k[e] = (int)0x80000000; }

    // prologue end: B0 landed (B1 may be in flight: vmcnt(2)), A writes visible.
    asm volatile("s_waitcnt vmcnt(2) lgkmcnt(0)\n\ts_barrier" ::: "memory");

    f32x4 acc[4][4];
    f16x8 af[4];
    // preload step-0 A fragments (covered by phase-0's lgkmcnt(0))
    #pragma unroll
    for (int rt = 0; rt < 4; ++rt) af[rt] = *(const f16x8*)&Asl[0][aoff[rt]];

    int bb = 0, sb = 2;      // current B buffer (s%3), stage buffer ((s+2)%3)
    int stct = 0, stj = 2;   // stage target = s+2 as (ct, j)

    for (int ct = 0; ct < NCT; ++ct) {
      for (int j = 0; j < NKS; ++j) {
        const unsigned short* Bb = Bsl[bb];
        const int jn = (j + 1) % NKS;   // next step's A tile (resident)

        // ---------- phase 0 ----------
        // af prefetched a step ago; Bb validated at the previous end barrier.
        f16x8 bg[2];
        bg[0] = *(const f16x8*)&Bb[boff[0]];
        bg[1] = *(const f16x8*)&Bb[boff[1]];
        if (stct < NCT) stageB(stct, stj, sb);

        if (j == 0) {
            #pragma unroll
            for (int i = 0; i < 4; ++i)
                #pragma unroll
                for (int jj = 0; jj < 4; ++jj) acc[i][jj] = (f32x4){0.f, 0.f, 0.f, 0.f};
        }

        asm volatile("s_waitcnt lgkmcnt(0)" ::: "memory");
        __builtin_amdgcn_sched_barrier(0);
        __builtin_amdgcn_s_setprio(1);
        #pragma unroll
        for (int rt = 0; rt < 4; ++rt)
            #pragma unroll
            for (int cf = 0; cf < 2; ++cf)
                acc[rt][cf] = __builtin_amdgcn_mfma_f32_16x16x32_f16(af[rt], bg[cf], acc[rt][cf], 0, 0, 0);
        __builtin_amdgcn_s_setprio(0);

        // ---------- phase 1 ----------
        f16x8 bh[2];
        bh[0] = *(const f16x8*)&Bb[boff[2]];
        bh[1] = *(const f16x8*)&Bb[boff[3]];

        asm volatile("s_waitcnt lgkmcnt(0)" ::: "memory");
        __builtin_amdgcn_sched_barrier(0);
        __builtin_amdgcn_s_setprio(1);
        #pragma unroll
        for (int rt = 0; rt < 4; ++rt)
            #pragma unroll
            for (int cf = 0; cf < 2; ++cf)
                acc[rt][cf + 2] = __builtin_amdgcn_mfma_f32_16x16x32_f16(af[rt], bh[cf], acc[rt][cf + 2], 0, 0, 0);
        __builtin_amdgcn_s_setprio(0);
        __builtin_amdgcn_sched_barrier(0);

        // ---------- tail: prefetch next step's A frags (A resident; WAR
        // after phase-1 consumers keeps ordering) ----------
        #pragma unroll
        for (int rt = 0; rt < 4; ++rt) af[rt] = *(const f16x8*)&Asl[jn][aoff[rt]];

        // fold at end of column tile (7 low mantissa bits carry (ct,cf);
        // chop ~8e-6 << 4e-4 fp64-refine gate)
        if (j == NKS - 1) {
            #pragma unroll
            for (int cf = 0; cf < 4; ++cf) {
                const int inv7 = 0x7F ^ ((ct << 2) | cf);   // wave-uniform
                #pragma unroll
                for (int rt = 0; rt < 4; ++rt)
                    #pragma unroll
                    for (int r = 0; r < 4; ++r) {
                        int key = (__float_as_int(acc[rt][cf][r]) & ~0x7F) | inv7;
                        kfold(t1k[rt * 4 + r], t2k[rt * 4 + r], key);
                    }
            }
        }

        // ---------- end-of-step sync: validate B ring slot for s+1 ----------
        // outstanding stages here: {s+1, s+2} (2 loads each, clipped at end).
        if (ct < NCT - 1 || j < NKS - 2) {
            asm volatile("s_waitcnt vmcnt(2)\n\ts_barrier" ::: "memory");
        } else if (j == NKS - 2) {
            asm volatile("s_waitcnt vmcnt(0)\n\ts_barrier" ::: "memory");
        } // last step: no barrier (epilogue __syncthreads covers)

        if (stct < NCT && ++stj == NKS) { stj = 0; ++stct; }
        if (++bb == 3) bb = 0;
        if (++sb == 3) sb = 0;
      }
    }

    // ---- decode keys -> (value, index) ----
    float p1v[16], p2v[16];
    int   p1i[16], p2i[16];
    #pragma unroll
    for (int e = 0; e < 16; ++e) {
        p1v[e] = __int_as_float(t1k[e] & ~0x7F);
        int e7 = 0x7F ^ (t1k[e] & 0x7F);
        p1i[e] = ((e7 >> 2) << 7) + wc * 64 + ((e7 & 3) << 4) + lo4;
        p2v[e] = __int_as_float(t2k[e] & ~0x7F);
        int e7b = 0x7F ^ (t2k[e] & 0x7F);
        p2i[e] = ((e7b >> 2) << 7) + wc * 64 + ((e7b & 3) << 4) + lo4;
    }

    // intra-wave butterfly top-2 reduce across the 16 col-lanes of each frag row
    #pragma unroll
    for (int e = 0; e < 16; ++e) {
        #pragma unroll
        for (int m = 1; m < 16; m <<= 1) {
            float ov1 = __shfl_xor(p1v[e], m);
            int   oi1 = __shfl_xor(p1i[e], m);
            float ov2 = __shfl_xor(p2v[e], m);
            int   oi2 = __shfl_xor(p2i[e], m);
            merge_top2(p1v[e], p1i[e], p2v[e], p2i[e], ov1, oi1, ov2, oi2);
        }
    }

    // cross-wave (column-half) merge via LDS scratch (reuse Asl; pipeline drained)
    __syncthreads();
    float* r1v = (float*)Asl;          // [128][2]
    float* r2v = r1v + 256;
    int*   r1i = (int*)(r2v + 256);
    int*   r2i = r1i + 256;
    if (lo4 == 0) {
        #pragma unroll
        for (int rt = 0; rt < 4; ++rt)
            #pragma unroll
            for (int r = 0; r < 4; ++r) {
                const int e = rt * 4 + r;
                int row = wr * 64 + rt * 16 + hi4 * 4 + r;   // 0..127
                r1v[row * 2 + wc] = p1v[e]; r1i[row * 2 + wc] = p1i[e];
                r2v[row * 2 + wc] = p2v[e]; r2i[row * 2 + wc] = p2i[e];
            }
    }
    __syncthreads();
    if (t < 128) {
        float v1 = r1v[t * 2], v2 = r2v[t * 2];
        int   i1 = r1i[t * 2], i2 = r2i[t * 2];
        merge_top2(v1, i1, v2, i2, r1v[t * 2 + 1], r1i[t * 2 + 1],
                                   r2v[t * 2 + 1], r2i[t * 2 + 1]);
        int grow = m0 + t;
        o1v[grow] = v1; o1i[grow] = i1;
        o2v[grow] = v2; o2i[grow] = i2;
    }
}

// ---------------- fp64 refinement of near-tie argmax ----------------
__global__ __launch_bounds__(256) void refine_kernel(
    const float* __restrict__ pixels, const float* __restrict__ codebook,
    const float* __restrict__ o1v, const int* __restrict__ o1i,
    const float* __restrict__ o2v, const int* __restrict__ o2i,
    int* __restrict__ idx_out, float* __restrict__ idxf_out)
{
    int row = blockIdx.x * 256 + threadIdx.x;
    if (row >= MROWS) return;
    float v1 = o1v[row], v2 = o2v[row];
    int   i1 = o1i[row], i2 = o2i[row];
    int idx = i1;
    if (v1 - v2 <= 4e-4f) {   // 20-sigma of the fp16 single-term sim error
        int b = row >> 6, p = row & 63;
        int gr = p >> 3, gc = p & 7;
        const float* pb = pixels + (size_t)b * 3 * 4096 + gr * 8 * 64 + gc * 8;
        const float* c1 = codebook + (size_t)i1 * PDIM;
        const float* c2 = codebook + (size_t)i2 * PDIM;
        double s1 = 0.0, s2 = 0.0;
        for (int d = 0; d < PDIM; ++d) {
            int ch = d >> 6, r = (d >> 3) & 7, c = d & 7;
            double x = (double)pb[ch * 4096 + r * 64 + c];
            s1 += x * (double)c1[d];
            s2 += x * (double)c2[d];
        }
        if (s2 > s1 || (s2 == s1 && i2 < i1)) idx = i2;
    }
    idx_out[row] = idx;
    idxf_out[row] = (float)idx;
}

// ---------------- fused z_real / z_local / z_vsa ----------------
__global__ __launch_bounds__(256) void zv_kernel(
    const float* __restrict__ emb, const float* __restrict__ vsa,
    const float* __restrict__ roles, const int* __restrict__ idx,
    float* __restrict__ z_real, float* __restrict__ z_local,
    float* __restrict__ z_vsa)
{
    __shared__ int sidx[64];
    int b = blockIdx.x, t = threadIdx.x;
    if (t < 64) sidx[t] = idx[b * 64 + t];
    __syncthreads();
    float s[8], sl[8];
    #pragma unroll
    for (int j = 0; j < 8; ++j) { s[j] = 0.f; sl[j] = 0.f; }
    for (int p = 0; p < 64; ++p) {
        int gr = p >> 3, gc = p & 7;
        bool ag = (gr >= 3 && gr < 6 && gc >= 3 && gc < 6);
        const float* er = emb + (size_t)sidx[p] * EDIM + t * 8;
        float v[8];
        *(float4*)&v[0] = *(const float4*)er;
        *(float4*)&v[4] = *(const float4*)(er + 4);
        #pragma unroll
        for (int j = 0; j < 8; ++j) s[j] += v[j];
        if (ag) {
            #pragma unroll
            for (int j = 0; j < 8; ++j) sl[j] += v[j];
        }
    }
    float* zr = z_real + (size_t)b * EDIM + t * 8;
    float* zl = z_local + (size_t)b * EDIM + t * 8;
    #pragma unroll
    for (int j = 0; j < 8; ++j) {
        zr[j] = s[j] * (1.f / 64.f);
        zl[j] = sl[j] * (1.f / 9.f);
    }

    // z_vsa over the 16 central patches
    float cnt[8];
    #pragma unroll
    for (int j = 0; j < 8; ++j) cnt[j] = 0.f;
    for (int cp = 0; cp < 16; ++cp) {
        int p = (2 + (cp >> 2)) * 8 + 2 + (cp & 3);
        const float* vr = vsa + (size_t)sidx[p] * VDIM + t * 8;
        const float* pr = roles + (size_t)p * VDIM + t * 8;
        float a[8], r[8];
        *(float4*)&a[0] = *(const float4*)vr;
        *(float4*)&a[4] = *(const float4*)(vr + 4);
        *(float4*)&r[0] = *(const float4*)pr;
        *(float4*)&r[4] = *(const float4*)(pr + 4);
        #pragma unroll
        for (int j = 0; j < 8; ++j) cnt[j] += (a[j] != r[j]) ? 1.f : 0.f;
    }
    #pragma unroll
    for (int j = 0; j < 8; ++j)
        z_vsa[(size_t)b * VDIM + t * 8 + j] = cnt[j] > 8.f ? 1.f : 0.f;
}

extern "C" void kernel_launch(void* const* d_in, const int* in_sizes, int n_in,
                              void* d_out, int out_size, void* d_ws, size_t ws_size,
                              hipStream_t stream) {
    const float* pixels         = (const float*)d_in[0];
    const float* codebook       = (const float*)d_in[1];
    const float* embeddings     = (const float*)d_in[2];
    const float* codebook_vsa   = (const float*)d_in[3];
    const float* position_roles = (const float*)d_in[4];

    float* out     = (float*)d_out;
    float* z_real  = out;                 // 1024*2048
    float* z_vsa   = out + 2097152;       // 1024*2048
    float* idxf    = out + 4194304;       // 1024*64
    float* z_local = out + 4259840;       // 1024*2048

    char* ws = (char*)d_ws;
    unsigned short* Bh = (unsigned short*)(ws);                      // 1572864 B
    float* o1v = (float*)(ws + 1572864);
    int*   o1i = (int*)  (ws + 1835008);
    float* o2v = (float*)(ws + 2097152);
    int*   o2i = (int*)  (ws + 2359296);
    int*   idxws = (int*)(ws + 2621440);

    prep_codebook_kernel<<<KCODES * PDIM / 8 / 256, 256, 0, stream>>>(codebook, Bh);

    gemm_top2_kernel<<<MROWS / 128, 256, 0, stream>>>(pixels, Bh, o1v, o1i, o2v, o2i);

    refine_kernel<<<MROWS / 256, 256, 0, stream>>>(pixels, codebook,
        o1v, o1i, o2v, o2i, idxws, idxf);
    zv_kernel<<<NIMG, 256, 0, stream>>>(embeddings, codebook_vsa, position_roles,
        idxws, z_real, z_local, z_vsa);
}

// Round 19
// 192.277 us; speedup vs baseline: 1.0548x; 1.0548x over previous
//
#include <hip/hip_runtime.h>
#include <hip/hip_bf16.h>
#include <math.h>

#define NIMG 1024
#define NPATCH 64
#define PDIM 192
#define KCODES 4096
#define EDIM 2048
#define VDIM 2048
#define MROWS (NIMG * NPATCH)   // 65536
#define KP 192                  // fp16 single-term: K = 192
#define NKS 6                   // K-steps (BK=32) per column tile
#define NCT 16                  // column tiles of 256 codes

typedef _Float16 f16x8 __attribute__((ext_vector_type(8)));
typedef __attribute__((ext_vector_type(4))) float f32x4;

__device__ __forceinline__ void gload_lds16(const void* g, void* l) {
    __builtin_amdgcn_global_load_lds(
        (const __attribute__((address_space(1))) unsigned int*)g,
        (__attribute__((address_space(3))) unsigned int*)l,
        16, 0, 0);
}

__device__ __forceinline__ void merge_top2(float& v1, int& i1, float& v2, int& i2,
                                           float ov1, int oi1, float ov2, int oi2) {
    bool aw = (v1 > ov1) || (v1 == ov1 && i1 < oi1);
    float w1v = aw ? v1 : ov1;  int w1i = aw ? i1 : oi1;
    float c2v = aw ? v2 : ov2;  int c2i = aw ? i2 : oi2;   // winner's own #2
    float l1v = aw ? ov1 : v1;  int l1i = aw ? oi1 : i1;   // loser's #1
    bool bw = (c2v > l1v) || (c2v == l1v && c2i < l1i);
    v1 = w1v; i1 = w1i;
    v2 = bw ? c2v : l1v; i2 = bw ? c2i : l1i;
}

// packed-key top-2 fold: 3 VALU (min_i32 + 2 max_i32)
__device__ __forceinline__ void kfold(int& t1, int& t2, int key) {
    int m = (key < t1) ? key : t1;
    t2 = (t2 > m) ? t2 : m;
    t1 = (t1 > key) ? t1 : key;
}

// ---------------- prep: codebook -> fp16, [4096][192], vectorized ----------------
__global__ __launch_bounds__(256) void prep_codebook_kernel(
    const float* __restrict__ cb, unsigned short* __restrict__ Bh)
{
    int i = (blockIdx.x * 256 + threadIdx.x) * 8;
    if (i >= KCODES * PDIM) return;
    float4 u = *(const float4*)(cb + i);
    float4 v = *(const float4*)(cb + i + 4);
    f16x8 h;
    h[0] = (_Float16)u.x; h[1] = (_Float16)u.y; h[2] = (_Float16)u.z; h[3] = (_Float16)u.w;
    h[4] = (_Float16)v.x; h[5] = (_Float16)v.y; h[6] = (_Float16)v.z; h[7] = (_Float16)v.w;
    *(f16x8*)(Bh + i) = h;
}

// ---------------- fp16 MFMA GEMM (16x16x32, K=192) + fused prep + top-2 ----
// Best-known configuration (r16, 191.8 us total / 153 us gemm):
// 256x256 block tile, 8 waves (4M x 2N), wave tile 64x128, BK=32.
// A panel (96 KB) built in-block from raw pixels, resident across all tiles.
// B 3-ring (48 KB), distance 2, counted vmcnt(2) at the single end-of-step
// barrier. 2-phase lgkm-fenced MFMA clusters with setprio. A-fragment SW
// pipeline: af for step s+1 is ds_read in step s's tail.
// __launch_bounds__(512,2) pins 256 regs/wave (2 waves/SIMD) — guards the
// r13/r14 spill cliff. Register budget: 108 VGPR + 128 acc = 236 <= 256.
// Local-optimum evidence: 2-blocks/CU (r11/r14/r18), BK=64 (r17), 32x32 MFMA
// (r9), no-fence (r12), distance variants (r10/r12) all regressed.
__global__ __launch_bounds__(512, 2) void gemm_top2_kernel(
    const float* __restrict__ pixels, const unsigned short* __restrict__ B,
    float* __restrict__ o1v, int* __restrict__ o1i,
    float* __restrict__ o2v, int* __restrict__ o2i)
{
    __shared__ unsigned short Asl[6][8192];   // 96 KB: A panel, tile j = K [32j,32j+32)
    __shared__ unsigned short Bsl[3][8192];   // 48 KB: B ring

    const int t = threadIdx.x;          // 0..511
    const int w = t >> 6;               // wave 0..7
    const int l = t & 63;
    const int lo4 = l & 15, hi4 = l >> 4;
    const int wr = w >> 1, wc = w & 1;  // 4M x 2N wave grid
    const int m0 = blockIdx.x * 256;

    // ---- fused A prep: 4 images -> normalized fp16 panel in LDS ----
    const float* pixb = pixels + (size_t)(m0 >> 6) * 12288;   // 4 images
    if (t < 256) {
        int p = t & 63;
        const float* pp = pixb + (size_t)(t >> 6) * 12288 + (p >> 3) * 512 + (p & 7) * 8;
        float s = 0.f;
        #pragma unroll
        for (int c3 = 0; c3 < 3; ++c3)
            #pragma unroll
            for (int rr = 0; rr < 8; ++rr) {
                const float* q = pp + c3 * 4096 + rr * 64;
                float4 u = *(const float4*)q, v = *(const float4*)(q + 4);
                s += u.x*u.x + u.y*u.y + u.z*u.z + u.w*u.w
                   + v.x*v.x + v.y*v.y + v.z*v.z + v.w*v.w;
            }
        ((float*)Asl)[t] = 1.f / fmaxf(sqrtf(s), 1e-8f);
    }
    __syncthreads();
    const int prow = t & 255;                       // my A row (0..255)
    const float rinv = ((float*)Asl)[prow];
    __syncthreads();                                // all inv reads done
    {
        int p = prow & 63;
        const float* pp = pixb + (size_t)(prow >> 6) * 12288 + (p >> 3) * 512 + (p & 7) * 8;
        const int ch0 = (t >> 8) * 12;
        #pragma unroll
        for (int q = 0; q < 12; ++q) {
            int ch = ch0 + q;                        // k-chunk 0..23 (8 elems)
            const float* src = pp + (ch >> 3) * 4096 + (ch & 7) * 64;
            float4 u = *(const float4*)src, v = *(const float4*)(src + 4);
            f16x8 hv;
            hv[0] = (_Float16)(u.x * rinv); hv[1] = (_Float16)(u.y * rinv);
            hv[2] = (_Float16)(u.z * rinv); hv[3] = (_Float16)(u.w * rinv);
            hv[4] = (_Float16)(v.x * rinv); hv[5] = (_Float16)(v.y * rinv);
            hv[6] = (_Float16)(v.z * rinv); hv[7] = (_Float16)(v.w * rinv);
            int j = ch >> 2, c = ch & 3;
            *(f16x8*)&Asl[j][prow * 32 + ((c ^ ((prow >> 1) & 3)) * 8)] = hv;
        }
    }

    // staging coords for B: thread t covers 16B chunk t (rows 0..127) and +512
    const int srow = t >> 2;                      // 0..127
    const int kc   = (t & 3) ^ ((srow >> 1) & 3); // swizzled k-chunk (involution)
    const unsigned short* b0b = B + (size_t)srow * KP + kc * 8;

    // LDS read offsets (ushort units within one 8192-ushort tile)
    int aoff[4], boff[8];
    #pragma unroll
    for (int rt = 0; rt < 4; ++rt) {
        int row = wr * 64 + rt * 16 + lo4;
        aoff[rt] = row * 32 + (hi4 ^ ((row >> 1) & 3)) * 8;
    }
    #pragma unroll
    for (int cf = 0; cf < 8; ++cf) {
        int col = wc * 128 + cf * 16 + lo4;
        boff[cf] = col * 32 + (hi4 ^ ((col >> 1) & 3)) * 8;
    }

    int t1k[16], t2k[16];
    #pragma unroll
    for (int e = 0; e < 16; ++e) { t1k[e] = (int)0x80000000; t2k[e] = (int)0x80000000; }

    auto stageB = [&](int sct, int sj, int sbuf) {
        char* Bd = (char*)Bsl[sbuf] + w * 1024;
        const unsigned short* gb = b0b + sct * (256 * KP) + sj * 32;
        gload_lds16(gb, Bd);
        gload_lds16(gb + 128 * KP, Bd + 8192);
    };

    // prologue: B steps 0,1 (4 loads). vmcnt(2): B0 landed; lgkmcnt(0): A
    // ds_writes visible; barrier globalizes both.
    stageB(0, 0, 0);
    stageB(0, 1, 1);
    asm volatile("s_waitcnt vmcnt(2) lgkmcnt(0)\n\ts_barrier" ::: "memory");

    f32x4 acc[4][8];
    f16x8 af[4];
    // preload step-0 A fragments (Asl[0]); covered by phase-0's lgkmcnt(0)
    #pragma unroll
    for (int rt = 0; rt < 4; ++rt) af[rt] = *(const f16x8*)&Asl[0][aoff[rt]];

    int bb = 0, sb = 2;      // current B buffer (s%3), stage buffer ((s+2)%3)
    int stct = 0, stj = 2;   // stage target = s+2 as (ct, j)

    for (int ct = 0; ct < NCT; ++ct) {
      for (int j = 0; j < NKS; ++j) {
        const unsigned short* Bb = Bsl[bb];
        const int jn = (j + 1) % NKS;   // next step's A tile (resident)

        // ---------- phase 0 ----------
        // af was prefetched in the previous step's tail (>=300 cyc + barrier
        // ago); Bb validated at the previous end-of-step barrier.
        f16x8 bg[4];
        #pragma unroll
        for (int cf = 0; cf < 4; ++cf) bg[cf] = *(const f16x8*)&Bb[boff[cf]];
        if (stct < NCT) stageB(stct, stj, sb);

        if (j == 0) {
            #pragma unroll
            for (int i = 0; i < 4; ++i)
                #pragma unroll
                for (int jj = 0; jj < 8; ++jj) acc[i][jj] = (f32x4){0.f, 0.f, 0.f, 0.f};
        }

        asm volatile("s_waitcnt lgkmcnt(0)" ::: "memory");
        __builtin_amdgcn_sched_barrier(0);
        __builtin_amdgcn_s_setprio(1);
        #pragma unroll
        for (int rt = 0; rt < 4; ++rt)
            #pragma unroll
            for (int cf = 0; cf < 4; ++cf)
                acc[rt][cf] = __builtin_amdgcn_mfma_f32_16x16x32_f16(af[rt], bg[cf], acc[rt][cf], 0, 0, 0);
        __builtin_amdgcn_s_setprio(0);

        // ---------- phase 1 ----------
        f16x8 bh[4];
        #pragma unroll
        for (int cf = 0; cf < 4; ++cf) bh[cf] = *(const f16x8*)&Bb[boff[cf + 4]];

        asm volatile("s_waitcnt lgkmcnt(0)" ::: "memory");
        __builtin_amdgcn_sched_barrier(0);
        __builtin_amdgcn_s_setprio(1);
        #pragma unroll
        for (int rt = 0; rt < 4; ++rt)
            #pragma unroll
            for (int cf = 0; cf < 4; ++cf)
                acc[rt][cf + 4] = __builtin_amdgcn_mfma_f32_16x16x32_f16(af[rt], bh[cf], acc[rt][cf + 4], 0, 0, 0);
        __builtin_amdgcn_s_setprio(0);
        __builtin_amdgcn_sched_barrier(0);

        // ---------- tail: prefetch next step's A frags (WAR on af keeps
        // ordering after the phase-1 MFMAs); latency hides under fold +
        // barrier + next phase-0's B reads ----------
        #pragma unroll
        for (int rt = 0; rt < 4; ++rt) af[rt] = *(const f16x8*)&Asl[jn][aoff[rt]];

        // fold at end of column tile (7 low mantissa bits carry (ct,cf);
        // chop ~4e-6 << 4e-4 fp64-refine gate)
        if (j == NKS - 1) {
            #pragma unroll
            for (int cf = 0; cf < 8; ++cf) {
                const int inv7 = 0x7F ^ ((ct << 3) | cf);   // wave-uniform
                #pragma unroll
                for (int rt = 0; rt < 4; ++rt)
                    #pragma unroll
                    for (int r = 0; r < 4; ++r) {
                        int key = (__float_as_int(acc[rt][cf][r]) & ~0x7F) | inv7;
                        kfold(t1k[rt * 4 + r], t2k[rt * 4 + r], key);
                    }
            }
        }

        // ---------- end-of-step sync: validate B ring slot for s+1 ----------
        // outstanding stages here: {s+1, s+2} (2 loads each, clipped at end).
        if (ct < NCT - 1 || j < NKS - 2) {
            asm volatile("s_waitcnt vmcnt(2)\n\ts_barrier" ::: "memory");
        } else if (j == NKS - 2) {
            asm volatile("s_waitcnt vmcnt(0)\n\ts_barrier" ::: "memory");
        } // last step: no barrier (epilogue __syncthreads covers)

        if (stct < NCT && ++stj == NKS) { stj = 0; ++stct; }
        if (++bb == 3) bb = 0;
        if (++sb == 3) sb = 0;
      }
    }

    // ---- decode keys -> (value, index) ----
    float p1v[16], p2v[16];
    int   p1i[16], p2i[16];
    #pragma unroll
    for (int e = 0; e < 16; ++e) {
        p1v[e] = __int_as_float(t1k[e] & ~0x7F);
        int lo7 = 0x7F ^ (t1k[e] & 0x7F);
        p1i[e] = ((lo7 >> 3) << 8) + wc * 128 + ((lo7 & 7) << 4) + lo4;
        p2v[e] = __int_as_float(t2k[e] & ~0x7F);
        int lo7b = 0x7F ^ (t2k[e] & 0x7F);
        p2i[e] = ((lo7b >> 3) << 8) + wc * 128 + ((lo7b & 7) << 4) + lo4;
    }

    // intra-wave butterfly top-2 reduce across the 16 col-lanes of each frag row
    #pragma unroll
    for (int e = 0; e < 16; ++e) {
        #pragma unroll
        for (int m = 1; m < 16; m <<= 1) {
            float ov1 = __shfl_xor(p1v[e], m);
            int   oi1 = __shfl_xor(p1i[e], m);
            float ov2 = __shfl_xor(p2v[e], m);
            int   oi2 = __shfl_xor(p2i[e], m);
            merge_top2(p1v[e], p1i[e], p2v[e], p2i[e], ov1, oi1, ov2, oi2);
        }
    }

    // cross-wave (column-half) merge via LDS scratch (reuse Asl; pipeline drained)
    __syncthreads();
    float* r1v = (float*)Asl;          // [256][2]
    float* r2v = r1v + 512;
    int*   r1i = (int*)(r2v + 512);
    int*   r2i = r1i + 512;
    if (lo4 == 0) {
        #pragma unroll
        for (int rt = 0; rt < 4; ++rt)
            #pragma unroll
            for (int r = 0; r < 4; ++r) {
                const int e = rt * 4 + r;
                int row = wr * 64 + rt * 16 + hi4 * 4 + r;   // 0..255
                r1v[row * 2 + wc] = p1v[e]; r1i[row * 2 + wc] = p1i[e];
                r2v[row * 2 + wc] = p2v[e]; r2i[row * 2 + wc] = p2i[e];
            }
    }
    __syncthreads();
    if (t < 256) {
        float v1 = r1v[t * 2], v2 = r2v[t * 2];
        int   i1 = r1i[t * 2], i2 = r2i[t * 2];
        merge_top2(v1, i1, v2, i2, r1v[t * 2 + 1], r1i[t * 2 + 1],
                                   r2v[t * 2 + 1], r2i[t * 2 + 1]);
        int grow = m0 + t;
        o1v[grow] = v1; o1i[grow] = i1;
        o2v[grow] = v2; o2i[grow] = i2;
    }
}

// ---------------- fp64 refinement of near-tie argmax ----------------
__global__ __launch_bounds__(256) void refine_kernel(
    const float* __restrict__ pixels, const float* __restrict__ codebook,
    const float* __restrict__ o1v, const int* __restrict__ o1i,
    const float* __restrict__ o2v, const int* __restrict__ o2i,
    int* __restrict__ idx_out, float* __restrict__ idxf_out)
{
    int row = blockIdx.x * 256 + threadIdx.x;
    if (row >= MROWS) return;
    float v1 = o1v[row], v2 = o2v[row];
    int   i1 = o1i[row], i2 = o2i[row];
    int idx = i1;
    if (v1 - v2 <= 4e-4f) {   // 20-sigma of the fp16 single-term sim error
        int b = row >> 6, p = row & 63;
        int gr = p >> 3, gc = p & 7;
        const float* pb = pixels + (size_t)b * 3 * 4096 + gr * 8 * 64 + gc * 8;
        const float* c1 = codebook + (size_t)i1 * PDIM;
        const float* c2 = codebook + (size_t)i2 * PDIM;
        double s1 = 0.0, s2 = 0.0;
        for (int d = 0; d < PDIM; ++d) {
            int ch = d >> 6, r = (d >> 3) & 7, c = d & 7;
            double x = (double)pb[ch * 4096 + r * 64 + c];
            s1 += x * (double)c1[d];
            s2 += x * (double)c2[d];
        }
        if (s2 > s1 || (s2 == s1 && i2 < i1)) idx = i2;
    }
    idx_out[row] = idx;
    idxf_out[row] = (float)idx;
}

// ---------------- fused z_real / z_local / z_vsa ----------------
__global__ __launch_bounds__(256) void zv_kernel(
    const float* __restrict__ emb, const float* __restrict__ vsa,
    const float* __restrict__ roles, const int* __restrict__ idx,
    float* __restrict__ z_real, float* __restrict__ z_local,
    float* __restrict__ z_vsa)
{
    __shared__ int sidx[64];
    int b = blockIdx.x, t = threadIdx.x;
    if (t < 64) sidx[t] = idx[b * 64 + t];
    __syncthreads();
    float s[8], sl[8];
    #pragma unroll
    for (int j = 0; j < 8; ++j) { s[j] = 0.f; sl[j] = 0.f; }
    for (int p = 0; p < 64; ++p) {
        int gr = p >> 3, gc = p & 7;
        bool ag = (gr >= 3 && gr < 6 && gc >= 3 && gc < 6);
        const float* er = emb + (size_t)sidx[p] * EDIM + t * 8;
        float v[8];
        *(float4*)&v[0] = *(const float4*)er;
        *(float4*)&v[4] = *(const float4*)(er + 4);
        #pragma unroll
        for (int j = 0; j < 8; ++j) s[j] += v[j];
        if (ag) {
            #pragma unroll
            for (int j = 0; j < 8; ++j) sl[j] += v[j];
        }
    }
    float* zr = z_real + (size_t)b * EDIM + t * 8;
    float* zl = z_local + (size_t)b * EDIM + t * 8;
    #pragma unroll
    for (int j = 0; j < 8; ++j) {
        zr[j] = s[j] * (1.f / 64.f);
        zl[j] = sl[j] * (1.f / 9.f);
    }

    // z_vsa over the 16 central patches
    float cnt[8];
    #pragma unroll
    for (int j = 0; j < 8; ++j) cnt[j] = 0.f;
    for (int cp = 0; cp < 16; ++cp) {
        int p = (2 + (cp >> 2)) * 8 + 2 + (cp & 3);
        const float* vr = vsa + (size_t)sidx[p] * VDIM + t * 8;
        const float* pr = roles + (size_t)p * VDIM + t * 8;
        float a[8], r[8];
        *(float4*)&a[0] = *(const float4*)vr;
        *(float4*)&a[4] = *(const float4*)(vr + 4);
        *(float4*)&r[0] = *(const float4*)pr;
        *(float4*)&r[4] = *(const float4*)(pr + 4);
        #pragma unroll
        for (int j = 0; j < 8; ++j) cnt[j] += (a[j] != r[j]) ? 1.f : 0.f;
    }
    #pragma unroll
    for (int j = 0; j < 8; ++j)
        z_vsa[(size_t)b * VDIM + t * 8 + j] = cnt[j] > 8.f ? 1.f : 0.f;
}

extern "C" void kernel_launch(void* const* d_in, const int* in_sizes, int n_in,
                              void* d_out, int out_size, void* d_ws, size_t ws_size,
                              hipStream_t stream) {
    const float* pixels         = (const float*)d_in[0];
    const float* codebook       = (const float*)d_in[1];
    const float* embeddings     = (const float*)d_in[2];
    const float* codebook_vsa   = (const float*)d_in[3];
    const float* position_roles = (const float*)d_in[4];

    float* out     = (float*)d_out;
    float* z_real  = out;                 // 1024*2048
    float* z_vsa   = out + 2097152;       // 1024*2048
    float* idxf    = out + 4194304;       // 1024*64
    float* z_local = out + 4259840;       // 1024*2048

    char* ws = (char*)d_ws;
    unsigned short* Bh = (unsigned short*)(ws);                      // 1572864 B
    float* o1v = (float*)(ws + 1572864);
    int*   o1i = (int*)  (ws + 1835008);
    float* o2v = (float*)(ws + 2097152);
    int*   o2i = (int*)  (ws + 2359296);
    int*   idxws = (int*)(ws + 2621440);

    prep_codebook_kernel<<<KCODES * PDIM / 8 / 256, 256, 0, stream>>>(codebook, Bh);

    gemm_top2_kernel<<<MROWS / 256, 512, 0, stream>>>(pixels, Bh, o1v, o1i, o2v, o2i);

    refine_kernel<<<MROWS / 256, 256, 0, stream>>>(pixels, codebook,
        o1v, o1i, o2v, o2i, idxws, idxf);
    zv_kernel<<<NIMG, 256, 0, stream>>>(embeddings, codebook_vsa, position_roles,
        idxws, z_real, z_local, z_vsa);
}

// Round 20
// 188.741 us; speedup vs baseline: 1.0746x; 1.0187x over previous
//
#include <hip/hip_runtime.h>
#include <hip/hip_bf16.h>
#include <math.h>

#define NIMG 1024
#define NPATCH 64
#define PDIM 192
#define KCODES 4096
#define EDIM 2048
#define VDIM 2048
#define MROWS (NIMG * NPATCH)   // 65536
#define KP 192                  // fp16 single-term: K = 192
#define NKS 6                   // K-steps (BK=32) per column tile
#define NCT 16                  // column tiles of 256 codes

typedef _Float16 f16x8 __attribute__((ext_vector_type(8)));
typedef __attribute__((ext_vector_type(4))) float f32x4;

__device__ __forceinline__ void gload_lds16(const void* g, void* l) {
    __builtin_amdgcn_global_load_lds(
        (const __attribute__((address_space(1))) unsigned int*)g,
        (__attribute__((address_space(3))) unsigned int*)l,
        16, 0, 0);
}

__device__ __forceinline__ void merge_top2(float& v1, int& i1, float& v2, int& i2,
                                           float ov1, int oi1, float ov2, int oi2) {
    bool aw = (v1 > ov1) || (v1 == ov1 && i1 < oi1);
    float w1v = aw ? v1 : ov1;  int w1i = aw ? i1 : oi1;
    float c2v = aw ? v2 : ov2;  int c2i = aw ? i2 : oi2;   // winner's own #2
    float l1v = aw ? ov1 : v1;  int l1i = aw ? oi1 : i1;   // loser's #1
    bool bw = (c2v > l1v) || (c2v == l1v && c2i < l1i);
    v1 = w1v; i1 = w1i;
    v2 = bw ? c2v : l1v; i2 = bw ? c2i : l1i;
}

// packed-key top-2 fold: 3 VALU (min_i32 + 2 max_i32)
__device__ __forceinline__ void kfold(int& t1, int& t2, int key) {
    int m = (key < t1) ? key : t1;
    t2 = (t2 > m) ? t2 : m;
    t1 = (t1 > key) ? t1 : key;
}

// ---------------- prep: codebook -> fp16, [4096][192], vectorized ----------------
__global__ __launch_bounds__(256) void prep_codebook_kernel(
    const float* __restrict__ cb, unsigned short* __restrict__ Bh)
{
    int i = (blockIdx.x * 256 + threadIdx.x) * 8;
    if (i >= KCODES * PDIM) return;
    float4 u = *(const float4*)(cb + i);
    float4 v = *(const float4*)(cb + i + 4);
    f16x8 h;
    h[0] = (_Float16)u.x; h[1] = (_Float16)u.y; h[2] = (_Float16)u.z; h[3] = (_Float16)u.w;
    h[4] = (_Float16)v.x; h[5] = (_Float16)v.y; h[6] = (_Float16)v.z; h[7] = (_Float16)v.w;
    *(f16x8*)(Bh + i) = h;
}

// ---------------- fp16 MFMA GEMM + fused prep + top-2 + fp64 refine ----
// r16 structure verbatim (best verified: 192 us total / 154 us gemm):
// 256x256 block tile, 8 waves (4M x 2N), wave tile 64x128, BK=32.
// A panel (96 KB) built in-block from raw pixels, resident; B 3-ring (48 KB),
// distance 2, counted vmcnt(2) at the single end-of-step barrier; 2-phase
// lgkm-fenced MFMA clusters with setprio; A-fragment SW pipeline.
// NEW (r20): refine fused into the epilogue — each block owns its 256 rows'
// FINAL top-2 (covers all 4096 codes), so the gap-check + rare fp64 rescue
// is block-local. Deletes the refine launch and the 1 MB top-2 round-trip.
// __launch_bounds__(512,2): 108 VGPR + 128 acc = 236 <= 256 (2 waves/SIMD).
__global__ __launch_bounds__(512, 2) void gemm_top2_kernel(
    const float* __restrict__ pixels, const unsigned short* __restrict__ B,
    const float* __restrict__ codebook,
    int* __restrict__ idx_out, float* __restrict__ idxf_out)
{
    __shared__ unsigned short Asl[6][8192];   // 96 KB: A panel, tile j = K [32j,32j+32)
    __shared__ unsigned short Bsl[3][8192];   // 48 KB: B ring

    const int t = threadIdx.x;          // 0..511
    const int w = t >> 6;               // wave 0..7
    const int l = t & 63;
    const int lo4 = l & 15, hi4 = l >> 4;
    const int wr = w >> 1, wc = w & 1;  // 4M x 2N wave grid
    const int m0 = blockIdx.x * 256;

    // ---- fused A prep: 4 images -> normalized fp16 panel in LDS ----
    const float* pixb = pixels + (size_t)(m0 >> 6) * 12288;   // 4 images
    if (t < 256) {
        int p = t & 63;
        const float* pp = pixb + (size_t)(t >> 6) * 12288 + (p >> 3) * 512 + (p & 7) * 8;
        float s = 0.f;
        #pragma unroll
        for (int c3 = 0; c3 < 3; ++c3)
            #pragma unroll
            for (int rr = 0; rr < 8; ++rr) {
                const float* q = pp + c3 * 4096 + rr * 64;
                float4 u = *(const float4*)q, v = *(const float4*)(q + 4);
                s += u.x*u.x + u.y*u.y + u.z*u.z + u.w*u.w
                   + v.x*v.x + v.y*v.y + v.z*v.z + v.w*v.w;
            }
        ((float*)Asl)[t] = 1.f / fmaxf(sqrtf(s), 1e-8f);
    }
    __syncthreads();
    const int prow = t & 255;                       // my A row (0..255)
    const float rinv = ((float*)Asl)[prow];
    __syncthreads();                                // all inv reads done
    {
        int p = prow & 63;
        const float* pp = pixb + (size_t)(prow >> 6) * 12288 + (p >> 3) * 512 + (p & 7) * 8;
        const int ch0 = (t >> 8) * 12;
        #pragma unroll
        for (int q = 0; q < 12; ++q) {
            int ch = ch0 + q;                        // k-chunk 0..23 (8 elems)
            const float* src = pp + (ch >> 3) * 4096 + (ch & 7) * 64;
            float4 u = *(const float4*)src, v = *(const float4*)(src + 4);
            f16x8 hv;
            hv[0] = (_Float16)(u.x * rinv); hv[1] = (_Float16)(u.y * rinv);
            hv[2] = (_Float16)(u.z * rinv); hv[3] = (_Float16)(u.w * rinv);
            hv[4] = (_Float16)(v.x * rinv); hv[5] = (_Float16)(v.y * rinv);
            hv[6] = (_Float16)(v.z * rinv); hv[7] = (_Float16)(v.w * rinv);
            int j = ch >> 2, c = ch & 3;
            *(f16x8*)&Asl[j][prow * 32 + ((c ^ ((prow >> 1) & 3)) * 8)] = hv;
        }
    }

    // staging coords for B: thread t covers 16B chunk t (rows 0..127) and +512
    const int srow = t >> 2;                      // 0..127
    const int kc   = (t & 3) ^ ((srow >> 1) & 3); // swizzled k-chunk (involution)
    const unsigned short* b0b = B + (size_t)srow * KP + kc * 8;

    // LDS read offsets (ushort units within one 8192-ushort tile)
    int aoff[4], boff[8];
    #pragma unroll
    for (int rt = 0; rt < 4; ++rt) {
        int row = wr * 64 + rt * 16 + lo4;
        aoff[rt] = row * 32 + (hi4 ^ ((row >> 1) & 3)) * 8;
    }
    #pragma unroll
    for (int cf = 0; cf < 8; ++cf) {
        int col = wc * 128 + cf * 16 + lo4;
        boff[cf] = col * 32 + (hi4 ^ ((col >> 1) & 3)) * 8;
    }

    int t1k[16], t2k[16];
    #pragma unroll
    for (int e = 0; e < 16; ++e) { t1k[e] = (int)0x80000000; t2k[e] = (int)0x80000000; }

    auto stageB = [&](int sct, int sj, int sbuf) {
        char* Bd = (char*)Bsl[sbuf] + w * 1024;
        const unsigned short* gb = b0b + sct * (256 * KP) + sj * 32;
        gload_lds16(gb, Bd);
        gload_lds16(gb + 128 * KP, Bd + 8192);
    };

    // prologue: B steps 0,1 (4 loads). vmcnt(2): B0 landed; lgkmcnt(0): A
    // ds_writes visible; barrier globalizes both.
    stageB(0, 0, 0);
    stageB(0, 1, 1);
    asm volatile("s_waitcnt vmcnt(2) lgkmcnt(0)\n\ts_barrier" ::: "memory");

    f32x4 acc[4][8];
    f16x8 af[4];
    // preload step-0 A fragments (Asl[0]); covered by phase-0's lgkmcnt(0)
    #pragma unroll
    for (int rt = 0; rt < 4; ++rt) af[rt] = *(const f16x8*)&Asl[0][aoff[rt]];

    int bb = 0, sb = 2;      // current B buffer (s%3), stage buffer ((s+2)%3)
    int stct = 0, stj = 2;   // stage target = s+2 as (ct, j)

    for (int ct = 0; ct < NCT; ++ct) {
      for (int j = 0; j < NKS; ++j) {
        const unsigned short* Bb = Bsl[bb];
        const int jn = (j + 1) % NKS;   // next step's A tile (resident)

        // ---------- phase 0 ----------
        // af was prefetched in the previous step's tail (>=300 cyc + barrier
        // ago); Bb validated at the previous end-of-step barrier.
        f16x8 bg[4];
        #pragma unroll
        for (int cf = 0; cf < 4; ++cf) bg[cf] = *(const f16x8*)&Bb[boff[cf]];
        if (stct < NCT) stageB(stct, stj, sb);

        if (j == 0) {
            #pragma unroll
            for (int i = 0; i < 4; ++i)
                #pragma unroll
                for (int jj = 0; jj < 8; ++jj) acc[i][jj] = (f32x4){0.f, 0.f, 0.f, 0.f};
        }

        asm volatile("s_waitcnt lgkmcnt(0)" ::: "memory");
        __builtin_amdgcn_sched_barrier(0);
        __builtin_amdgcn_s_setprio(1);
        #pragma unroll
        for (int rt = 0; rt < 4; ++rt)
            #pragma unroll
            for (int cf = 0; cf < 4; ++cf)
                acc[rt][cf] = __builtin_amdgcn_mfma_f32_16x16x32_f16(af[rt], bg[cf], acc[rt][cf], 0, 0, 0);
        __builtin_amdgcn_s_setprio(0);

        // ---------- phase 1 ----------
        f16x8 bh[4];
        #pragma unroll
        for (int cf = 0; cf < 4; ++cf) bh[cf] = *(const f16x8*)&Bb[boff[cf + 4]];

        asm volatile("s_waitcnt lgkmcnt(0)" ::: "memory");
        __builtin_amdgcn_sched_barrier(0);
        __builtin_amdgcn_s_setprio(1);
        #pragma unroll
        for (int rt = 0; rt < 4; ++rt)
            #pragma unroll
            for (int cf = 0; cf < 4; ++cf)
                acc[rt][cf + 4] = __builtin_amdgcn_mfma_f32_16x16x32_f16(af[rt], bh[cf], acc[rt][cf + 4], 0, 0, 0);
        __builtin_amdgcn_s_setprio(0);
        __builtin_amdgcn_sched_barrier(0);

        // ---------- tail: prefetch next step's A frags (WAR on af keeps
        // ordering after the phase-1 MFMAs); latency hides under fold +
        // barrier + next phase-0's B reads ----------
        #pragma unroll
        for (int rt = 0; rt < 4; ++rt) af[rt] = *(const f16x8*)&Asl[jn][aoff[rt]];

        // fold at end of column tile (7 low mantissa bits carry (ct,cf);
        // chop ~4e-6 << 4e-4 fp64-refine gate)
        if (j == NKS - 1) {
            #pragma unroll
            for (int cf = 0; cf < 8; ++cf) {
                const int inv7 = 0x7F ^ ((ct << 3) | cf);   // wave-uniform
                #pragma unroll
                for (int rt = 0; rt < 4; ++rt)
                    #pragma unroll
                    for (int r = 0; r < 4; ++r) {
                        int key = (__float_as_int(acc[rt][cf][r]) & ~0x7F) | inv7;
                        kfold(t1k[rt * 4 + r], t2k[rt * 4 + r], key);
                    }
            }
        }

        // ---------- end-of-step sync: validate B ring slot for s+1 ----------
        // outstanding stages here: {s+1, s+2} (2 loads each, clipped at end).
        if (ct < NCT - 1 || j < NKS - 2) {
            asm volatile("s_waitcnt vmcnt(2)\n\ts_barrier" ::: "memory");
        } else if (j == NKS - 2) {
            asm volatile("s_waitcnt vmcnt(0)\n\ts_barrier" ::: "memory");
        } // last step: no barrier (epilogue __syncthreads covers)

        if (stct < NCT && ++stj == NKS) { stj = 0; ++stct; }
        if (++bb == 3) bb = 0;
        if (++sb == 3) sb = 0;
      }
    }

    // ---- decode keys -> (value, index) ----
    float p1v[16], p2v[16];
    int   p1i[16], p2i[16];
    #pragma unroll
    for (int e = 0; e < 16; ++e) {
        p1v[e] = __int_as_float(t1k[e] & ~0x7F);
        int lo7 = 0x7F ^ (t1k[e] & 0x7F);
        p1i[e] = ((lo7 >> 3) << 8) + wc * 128 + ((lo7 & 7) << 4) + lo4;
        p2v[e] = __int_as_float(t2k[e] & ~0x7F);
        int lo7b = 0x7F ^ (t2k[e] & 0x7F);
        p2i[e] = ((lo7b >> 3) << 8) + wc * 128 + ((lo7b & 7) << 4) + lo4;
    }

    // intra-wave butterfly top-2 reduce across the 16 col-lanes of each frag row
    #pragma unroll
    for (int e = 0; e < 16; ++e) {
        #pragma unroll
        for (int m = 1; m < 16; m <<= 1) {
            float ov1 = __shfl_xor(p1v[e], m);
            int   oi1 = __shfl_xor(p1i[e], m);
            float ov2 = __shfl_xor(p2v[e], m);
            int   oi2 = __shfl_xor(p2i[e], m);
            merge_top2(p1v[e], p1i[e], p2v[e], p2i[e], ov1, oi1, ov2, oi2);
        }
    }

    // cross-wave (column-half) merge via LDS scratch (reuse Asl; pipeline drained)
    __syncthreads();
    float* r1v = (float*)Asl;          // [256][2]
    float* r2v = r1v + 512;
    int*   r1i = (int*)(r2v + 512);
    int*   r2i = r1i + 512;
    if (lo4 == 0) {
        #pragma unroll
        for (int rt = 0; rt < 4; ++rt)
            #pragma unroll
            for (int r = 0; r < 4; ++r) {
                const int e = rt * 4 + r;
                int row = wr * 64 + rt * 16 + hi4 * 4 + r;   // 0..255
                r1v[row * 2 + wc] = p1v[e]; r1i[row * 2 + wc] = p1i[e];
                r2v[row * 2 + wc] = p2v[e]; r2i[row * 2 + wc] = p2i[e];
            }
    }
    __syncthreads();
    if (t < 256) {
        float v1 = r1v[t * 2], v2 = r2v[t * 2];
        int   i1 = r1i[t * 2], i2 = r2i[t * 2];
        merge_top2(v1, i1, v2, i2, r1v[t * 2 + 1], r1i[t * 2 + 1],
                                   r2v[t * 2 + 1], r2i[t * 2 + 1]);

        // ---- fused fp64 refine: block-local (this block saw all 4096 codes).
        // 4e-4 gate = 20-sigma of the fp16 single-term sim error; rare path.
        int idx = i1;
        if (v1 - v2 <= 4e-4f) {
            int grow = m0 + t;
            int b = grow >> 6, p = grow & 63;
            int gr = p >> 3, gc = p & 7;
            const float* pb = pixels + (size_t)b * 3 * 4096 + gr * 8 * 64 + gc * 8;
            const float* c1 = codebook + (size_t)i1 * PDIM;
            const float* c2 = codebook + (size_t)i2 * PDIM;
            double s1 = 0.0, s2 = 0.0;
            for (int d = 0; d < PDIM; ++d) {
                int ch = d >> 6, r = (d >> 3) & 7, c = d & 7;
                double x = (double)pb[ch * 4096 + r * 64 + c];
                s1 += x * (double)c1[d];
                s2 += x * (double)c2[d];
            }
            if (s2 > s1 || (s2 == s1 && i2 < i1)) idx = i2;
        }
        idx_out[m0 + t]  = idx;
        idxf_out[m0 + t] = (float)idx;
    }
}

// ---------------- fused z_real / z_local / z_vsa ----------------
__global__ __launch_bounds__(256) void zv_kernel(
    const float* __restrict__ emb, const float* __restrict__ vsa,
    const float* __restrict__ roles, const int* __restrict__ idx,
    float* __restrict__ z_real, float* __restrict__ z_local,
    float* __restrict__ z_vsa)
{
    __shared__ int sidx[64];
    int b = blockIdx.x, t = threadIdx.x;
    if (t < 64) sidx[t] = idx[b * 64 + t];
    __syncthreads();
    float s[8], sl[8];
    #pragma unroll
    for (int j = 0; j < 8; ++j) { s[j] = 0.f; sl[j] = 0.f; }
    for (int p = 0; p < 64; ++p) {
        int gr = p >> 3, gc = p & 7;
        bool ag = (gr >= 3 && gr < 6 && gc >= 3 && gc < 6);
        const float* er = emb + (size_t)sidx[p] * EDIM + t * 8;
        float v[8];
        *(float4*)&v[0] = *(const float4*)er;
        *(float4*)&v[4] = *(const float4*)(er + 4);
        #pragma unroll
        for (int j = 0; j < 8; ++j) s[j] += v[j];
        if (ag) {
            #pragma unroll
            for (int j = 0; j < 8; ++j) sl[j] += v[j];
        }
    }
    float* zr = z_real + (size_t)b * EDIM + t * 8;
    float* zl = z_local + (size_t)b * EDIM + t * 8;
    #pragma unroll
    for (int j = 0; j < 8; ++j) {
        zr[j] = s[j] * (1.f / 64.f);
        zl[j] = sl[j] * (1.f / 9.f);
    }

    // z_vsa over the 16 central patches
    float cnt[8];
    #pragma unroll
    for (int j = 0; j < 8; ++j) cnt[j] = 0.f;
    for (int cp = 0; cp < 16; ++cp) {
        int p = (2 + (cp >> 2)) * 8 + 2 + (cp & 3);
        const float* vr = vsa + (size_t)sidx[p] * VDIM + t * 8;
        const float* pr = roles + (size_t)p * VDIM + t * 8;
        float a[8], r[8];
        *(float4*)&a[0] = *(const float4*)vr;
        *(float4*)&a[4] = *(const float4*)(vr + 4);
        *(float4*)&r[0] = *(const float4*)pr;
        *(float4*)&r[4] = *(const float4*)(pr + 4);
        #pragma unroll
        for (int j = 0; j < 8; ++j) cnt[j] += (a[j] != r[j]) ? 1.f : 0.f;
    }
    #pragma unroll
    for (int j = 0; j < 8; ++j)
        z_vsa[(size_t)b * VDIM + t * 8 + j] = cnt[j] > 8.f ? 1.f : 0.f;
}

extern "C" void kernel_launch(void* const* d_in, const int* in_sizes, int n_in,
                              void* d_out, int out_size, void* d_ws, size_t ws_size,
                              hipStream_t stream) {
    const float* pixels         = (const float*)d_in[0];
    const float* codebook       = (const float*)d_in[1];
    const float* embeddings     = (const float*)d_in[2];
    const float* codebook_vsa   = (const float*)d_in[3];
    const float* position_roles = (const float*)d_in[4];

    float* out     = (float*)d_out;
    float* z_real  = out;                 // 1024*2048
    float* z_vsa   = out + 2097152;       // 1024*2048
    float* idxf    = out + 4194304;       // 1024*64
    float* z_local = out + 4259840;       // 1024*2048

    char* ws = (char*)d_ws;
    unsigned short* Bh = (unsigned short*)(ws);                      // 1572864 B
    int*   idxws = (int*)(ws + 1572864);                             //  262144 B

    prep_codebook_kernel<<<KCODES * PDIM / 8 / 256, 256, 0, stream>>>(codebook, Bh);

    gemm_top2_kernel<<<MROWS / 256, 512, 0, stream>>>(pixels, Bh, codebook,
        idxws, idxf);

    zv_kernel<<<NIMG, 256, 0, stream>>>(embeddings, codebook_vsa, position_roles,
        idxws, z_real, z_local, z_vsa);
}